// Round 1
// baseline (148.473 us; speedup 1.0000x reference)
//
#include <hip/hip_runtime.h>
#include <hip/hip_bf16.h>
#include <stdint.h>

// Problem constants
#define HH 256
#define WW 256
#define CIN 128
#define COUT 256
#define OHW 64516          // 254*254
#define KTOT 1152          // 128*9

#define BM 128
#define BN 256
#define BK 64
#define NSTEP 18           // KTOT / BK

typedef __attribute__((ext_vector_type(8))) short short8;
typedef __attribute__((ext_vector_type(4))) float float4v;
typedef __attribute__((ext_vector_type(4))) float f32x4;

__device__ __forceinline__ short f2bf(float f) {
    unsigned u = __builtin_bit_cast(unsigned, f);
    unsigned r = u + 0x7fffu + ((u >> 16) & 1u);   // RNE
    return (short)(r >> 16);
}

__device__ __forceinline__ short8 cvt8(float4v a, float4v b) {
    short8 r;
    r[0] = f2bf(a[0]); r[1] = f2bf(a[1]); r[2] = f2bf(a[2]); r[3] = f2bf(a[3]);
    r[4] = f2bf(b[0]); r[5] = f2bf(b[1]); r[6] = f2bf(b[2]); r[7] = f2bf(b[3]);
    return r;
}

// Prep: Wt[co][k'] = bf16(kernel_q[c*9+q][co]),  k' = q*128 + c  (bijective K-permute)
// int8-valued weights are exact in bf16.
__global__ void prep_weights(const int* __restrict__ kq, unsigned short* __restrict__ wt) {
    int tid = blockIdx.x * 256 + threadIdx.x;      // tid = k*256 + co  (coalesced read)
    if (tid >= KTOT * COUT) return;
    int k  = tid >> 8;
    int co = tid & 255;
    int c  = k / 9;
    int q  = k - c * 9;
    int kp = q * 128 + c;
    wt[co * KTOT + kp] = (unsigned short)f2bf((float)kq[tid]);
}

__global__ __launch_bounds__(512, 2) void conv_gemm(
    const float* __restrict__ x,
    const unsigned short* __restrict__ wt,
    const float* __restrict__ scale_p,
    const float* __restrict__ bias,
    float* __restrict__ out)
{
    // LDS: As [128 rows][64 k] bf16 (16 KB) + Bs [256 co][64 k] bf16 (32 KB), XOR-swizzled
    __shared__ __align__(16) char lds[BM * BK * 2 + BN * BK * 2];
    char* asb = lds;
    char* bsb = lds + BM * BK * 2;

    const int tid   = threadIdx.x;
    const int pbase = blockIdx.x * BM;

    // ---- A staging mapping: 4 threads per row, 16 floats each
    const int arow = tid >> 2;
    const int asub = tid & 3;
    int p = pbase + arow;
    if (p > OHW - 1) p = OHW - 1;                  // clamp: garbage rows, stores guarded
    const int oy = p / 254;
    const int ox = p - oy * 254;
    const float* xrow = x + (oy * WW + ox) * CIN + asub * 16;

    // ---- B staging mapping: 2 threads per co-row, 32 bf16 each
    const int bco  = tid >> 1;
    const int bsub = tid & 1;
    const unsigned short* wrow = wt + bco * KTOT + bsub * 32;

    // ---- wave/fragment mapping
    const int lane = tid & 63;
    const int wid  = tid >> 6;
    const int wr   = wid >> 2;     // 0..1  (row 64-tile)
    const int wc   = wid & 3;      // 0..3  (col 64-tile)
    const int lhi  = lane >> 4;    // 0..3
    const int llo  = lane & 15;

    f32x4 acc[4][4];
#pragma unroll
    for (int m = 0; m < 4; m++)
#pragma unroll
        for (int n = 0; n < 4; n++) acc[m][n] = (f32x4)0.f;

    for (int tk = 0; tk < NSTEP; ++tk) {
        const int q  = tk >> 1;
        const int c0 = (tk & 1) << 6;
        const int ki = q / 3;
        const int kj = q - ki * 3;

        // global loads (issued before barrier: overlap with previous compute)
        const float* src = xrow + (ki * WW + kj) * CIN + c0;
        float4v va0 = *(const float4v*)(src + 0);
        float4v va1 = *(const float4v*)(src + 4);
        float4v va2 = *(const float4v*)(src + 8);
        float4v va3 = *(const float4v*)(src + 12);

        const unsigned short* bsrc = wrow + tk * 64;
        short8 vb0 = *(const short8*)(bsrc + 0);
        short8 vb1 = *(const short8*)(bsrc + 8);
        short8 vb2 = *(const short8*)(bsrc + 16);
        short8 vb3 = *(const short8*)(bsrc + 24);

        __syncthreads();   // previous compute done before overwrite

        // A writes: row arow, k elems [asub*16 .. +15] -> two 16B chunks, swizzled
        {
            short8 w0 = cvt8(va0, va1);
            short8 w1 = cvt8(va2, va3);
            int base = arow * 128 + asub * 32;
            int swz  = (arow & 7) << 4;
            *(short8*)(asb + ((base +  0) ^ swz)) = w0;
            *(short8*)(asb + ((base + 16) ^ swz)) = w1;
        }
        // B writes: row bco, k elems [bsub*32 .. +31] -> four 16B chunks, swizzled
        {
            int base = bco * 128 + bsub * 64;
            int swz  = (bco & 7) << 4;
            *(short8*)(bsb + ((base +  0) ^ swz)) = vb0;
            *(short8*)(bsb + ((base + 16) ^ swz)) = vb1;
            *(short8*)(bsb + ((base + 32) ^ swz)) = vb2;
            *(short8*)(bsb + ((base + 48) ^ swz)) = vb3;
        }

        __syncthreads();

        // compute: BK=64 -> 2 MFMA K-slices of 32
#pragma unroll
        for (int kk = 0; kk < 2; ++kk) {
            short8 af[4], bfr[4];
#pragma unroll
            for (int m = 0; m < 4; m++) {
                int row  = wr * 64 + m * 16 + llo;
                int byte = row * 128 + kk * 64 + lhi * 16;
                byte ^= (row & 7) << 4;
                af[m] = *(const short8*)(asb + byte);
            }
#pragma unroll
            for (int n = 0; n < 4; n++) {
                int co   = wc * 64 + n * 16 + llo;
                int byte = co * 128 + kk * 64 + lhi * 16;
                byte ^= (co & 7) << 4;
                bfr[n] = *(const short8*)(bsb + byte);
            }
#pragma unroll
            for (int m = 0; m < 4; m++)
#pragma unroll
                for (int n = 0; n < 4; n++)
                    acc[m][n] = __builtin_amdgcn_mfma_f32_16x16x32_bf16(
                        af[m], bfr[n], acc[m][n], 0, 0, 0);
        }
    }

    // ---- epilogue: out[p][co] = acc * scale + bias[co]
    const float scl = scale_p[0];
#pragma unroll
    for (int n = 0; n < 4; n++) {
        const int col = wc * 64 + n * 16 + llo;
        const float bv = bias[col];
#pragma unroll
        for (int m = 0; m < 4; m++) {
            const int prow = pbase + wr * 64 + m * 16 + lhi * 4;
#pragma unroll
            for (int r = 0; r < 4; r++) {
                const int pp = prow + r;
                if (pp < OHW)
                    out[pp * COUT + col] = acc[m][n][r] * scl + bv;
            }
        }
    }
}

extern "C" void kernel_launch(void* const* d_in, const int* in_sizes, int n_in,
                              void* d_out, int out_size, void* d_ws, size_t ws_size,
                              hipStream_t stream) {
    const float* x      = (const float*)d_in[0];
    const int*   kq     = (const int*)d_in[1];
    const float* scale  = (const float*)d_in[2];
    const float* bias   = (const float*)d_in[3];
    float*       out    = (float*)d_out;
    unsigned short* wt  = (unsigned short*)d_ws;   // 1152*256*2 = 576 KB

    prep_weights<<<KTOT, 256, 0, stream>>>(kq, wt);

    const int nblk = (OHW + BM - 1) / BM;          // 505
    conv_gemm<<<nblk, 512, 0, stream>>>(x, wt, scale, bias, out);
}